// Round 3
// baseline (277.519 us; speedup 1.0000x reference)
//
#include <hip/hip_runtime.h>

// y = x @ W^T + bias; x:[65536,512] f32, W:[512,512] f32, bias:[512] f32.
// bf16 MFMA 16x16x32, fp32 acc. 128x128 tile, BK=32, 4 waves (2x2 of 64x64).
// R3: LDS double-buffer (1 barrier/tile), depth-2 register prefetch,
// W pre-converted to bf16 in d_ws, XCD swizzle, nontemporal Y stores.

#define BM 128
#define BN 128
#define BK 32
#define ABK 40  // 80 B row stride = 20 banks -> <=2-way conflicts (free)

typedef __bf16 bf16x8 __attribute__((ext_vector_type(8)));
typedef float f32x4 __attribute__((ext_vector_type(4)));

__global__ void cvt_w(const float* __restrict__ W, __bf16* __restrict__ Wb) {
  const int i = (blockIdx.x * 256 + threadIdx.x) * 8;
  f32x4 a = *(const f32x4*)(W + i);
  f32x4 b = *(const f32x4*)(W + i + 4);
  bf16x8 o;
#pragma unroll
  for (int e = 0; e < 4; ++e) { o[e] = (__bf16)a[e]; o[e + 4] = (__bf16)b[e]; }
  *(bf16x8*)(Wb + i) = o;
}

template <bool PREP>
__global__ __launch_bounds__(256, 3)
void linear_bf16_mfma(const float* __restrict__ X,
                      const void* __restrict__ Wsrc,
                      const float* __restrict__ bias,
                      float* __restrict__ Y) {
  constexpr int K = 512;
  constexpr int N = 512;
  constexpr int NT = K / BK;  // 16 K-tiles

  __shared__ __bf16 As[2][BM * ABK];
  __shared__ __bf16 Bs[2][BN * ABK];

  const int tid  = threadIdx.x;
  const int lane = tid & 63;
  const int wave = tid >> 6;

  // XCD swizzle: 4 N-sharers of one X row-tile land on the same XCD.
  const int lid = blockIdx.x;
  const int xcd = lid & 7;
  const int ii  = lid >> 3;
  const int bn  = (ii & 3) * BN;
  const int bm  = ((ii >> 2) * 8 + xcd) * BM;

  const int wm = (wave >> 1) * 64;
  const int wn = (wave & 1) * 64;

  // staging: thread t -> rows {srow, 64+srow}, k-cols scol..scol+7
  const int srow = tid >> 2;       // 0..63
  const int scol = (tid & 3) * 8;  // 0,8,16,24

  // MFMA A/B fragment: row = lane&15, k = (lane>>4)*8 + j
  const int mrow = lane & 15;
  const int kq   = (lane >> 4) * 8;

  const float* Xp = X + (size_t)(bm + srow) * K + scol;
  const __bf16* Wbp = PREP ? ((const __bf16*)Wsrc + (size_t)(bn + srow) * K + scol) : nullptr;
  const float*  Wfp = PREP ? nullptr : ((const float*)Wsrc + (size_t)(bn + srow) * K + scol);

  f32x4  aR[2][2][2];  // [set][pass][half]
  bf16x8 bR[2][2];     // [set][pass]      (PREP)
  f32x4  bRf[2][2][2]; // [set][pass][half] (fallback)

  auto issue = [&](int set, int kt) {
    const float* ga = Xp + kt * BK;
#pragma unroll
    for (int p = 0; p < 2; ++p) {
      aR[set][p][0] = *(const f32x4*)(ga + (size_t)p * 64 * K);
      aR[set][p][1] = *(const f32x4*)(ga + (size_t)p * 64 * K + 4);
    }
    if (PREP) {
      const __bf16* gb = Wbp + kt * BK;
#pragma unroll
      for (int p = 0; p < 2; ++p)
        bR[set][p] = *(const bf16x8*)(gb + (size_t)p * 64 * K);
    } else {
      const float* gb = Wfp + kt * BK;
#pragma unroll
      for (int p = 0; p < 2; ++p) {
        bRf[set][p][0] = *(const f32x4*)(gb + (size_t)p * 64 * K);
        bRf[set][p][1] = *(const f32x4*)(gb + (size_t)p * 64 * K + 4);
      }
    }
  };

  auto stage = [&](int set, int buf) {
#pragma unroll
    for (int p = 0; p < 2; ++p) {
      bf16x8 av;
#pragma unroll
      for (int e = 0; e < 4; ++e) {
        av[e]     = (__bf16)aR[set][p][0][e];
        av[e + 4] = (__bf16)aR[set][p][1][e];
      }
      const int r = p * 64 + srow;
      *(bf16x8*)(&As[buf][r * ABK + scol]) = av;
      if (PREP) {
        *(bf16x8*)(&Bs[buf][r * ABK + scol]) = bR[set][p];
      } else {
        bf16x8 bv;
#pragma unroll
        for (int e = 0; e < 4; ++e) {
          bv[e]     = (__bf16)bRf[set][p][0][e];
          bv[e + 4] = (__bf16)bRf[set][p][1][e];
        }
        *(bf16x8*)(&Bs[buf][r * ABK + scol]) = bv;
      }
    }
  };

  f32x4 acc[4][4] = {};

  auto compute = [&](int buf) {
    bf16x8 af[4], bfr[4];
#pragma unroll
    for (int i = 0; i < 4; ++i)
      af[i] = *(const bf16x8*)(&As[buf][(wm + i * 16 + mrow) * ABK + kq]);
#pragma unroll
    for (int j = 0; j < 4; ++j)
      bfr[j] = *(const bf16x8*)(&Bs[buf][(wn + j * 16 + mrow) * ABK + kq]);
#pragma unroll
    for (int i = 0; i < 4; ++i)
#pragma unroll
      for (int j = 0; j < 4; ++j)
        acc[i][j] = __builtin_amdgcn_mfma_f32_16x16x32_bf16(af[i], bfr[j],
                                                            acc[i][j], 0, 0, 0);
  };

  // prologue: tiles 0 and 1 in flight; tile 0 staged to buf0
  issue(0, 0);
  issue(1, 1);
  stage(0, 0);
  __syncthreads();

#pragma unroll
  for (int k = 0; k < NT; ++k) {
    if (k + 2 < NT) issue(k & 1, k + 2);   // refill freed set; ~full-iter distance
    compute(k & 1);
    if (k + 1 < NT) {
      stage((k + 1) & 1, (k + 1) & 1);     // waits only on the older set's loads
      __syncthreads();
    }
  }

  // epilogue: C/D layout col=lane&15 (n), row=(lane>>4)*4+reg (m)
  const int col0 = lane & 15;
  const int row0 = (lane >> 4) * 4;
#pragma unroll
  for (int j = 0; j < 4; ++j) {
    const int gc = bn + wn + j * 16 + col0;
    const float bj = bias[gc];
#pragma unroll
    for (int i = 0; i < 4; ++i) {
      const int gr = bm + wm + i * 16 + row0;
#pragma unroll
      for (int r = 0; r < 4; ++r)
        __builtin_nontemporal_store(acc[i][j][r] + bj,
                                    &Y[(size_t)(gr + r) * N + gc]);
    }
  }
}

extern "C" void kernel_launch(void* const* d_in, const int* in_sizes, int n_in,
                              void* d_out, int out_size, void* d_ws, size_t ws_size,
                              hipStream_t stream) {
  const float* X = (const float*)d_in[0];
  const float* W = (const float*)d_in[1];
  const float* b = (const float*)d_in[2];
  float* Y = (float*)d_out;

  if (ws_size >= (size_t)(512 * 512 * 2)) {
    __bf16* Wb = (__bf16*)d_ws;
    cvt_w<<<dim3(128), 256, 0, stream>>>(W, Wb);
    linear_bf16_mfma<true><<<dim3(2048), 256, 0, stream>>>(X, Wb, b, Y);
  } else {
    linear_bf16_mfma<false><<<dim3(2048), 256, 0, stream>>>(X, W, b, Y);
  }
}